// Round 1
// baseline (75.988 us; speedup 1.0000x reference)
//
#include <hip/hip_runtime.h>
#include <hip/hip_bf16.h>

// MDCA: for each of 4 CAMs [B=128, C=1000, H=14, W=14]:
//   avg_conf[c] = mean over (b,h,w) of cam[b,c,h,w]
//   avg_count[c] = bincount(target, C)[c] / B
//   out = mean_c |avg_conf[c] - avg_count[c]|
// Memory-bound: 401 MB read -> ~64 us floor at 6.3 TB/s.

constexpr int B  = 128;
constexpr int C  = 1000;
constexpr int HW = 196;   // 14*14
constexpr int HW4 = HW / 4;  // 49 float4 per (b,c) segment

// One block per (class c = blockIdx.x, cam = blockIdx.y).
// Sums cam[b, c, :, :] over all b, writes to sums[cam*C + c].
__global__ __launch_bounds__(256) void class_sum_kernel(
    const float* __restrict__ c0, const float* __restrict__ c1,
    const float* __restrict__ c2, const float* __restrict__ c3,
    float* __restrict__ sums)
{
    const int c   = blockIdx.x;
    const int cam = blockIdx.y;
    const float* __restrict__ src =
        (cam == 0) ? c0 : (cam == 1) ? c1 : (cam == 2) ? c2 : c3;

    float acc = 0.0f;
    // Flatten (b, j) over B*HW4 float4 loads. Consecutive threads ->
    // consecutive 16B within a 784B segment; 49-lane groups per segment.
    const int total4 = B * HW4;  // 6272
    for (int i = threadIdx.x; i < total4; i += 256) {
        const int b = i / HW4;          // magic-mul division
        const int j = i - b * HW4;
        const float4 v = *reinterpret_cast<const float4*>(
            src + (size_t)(b * C + c) * HW + (size_t)j * 4);
        acc += (v.x + v.y) + (v.z + v.w);
    }

    // Wave (64-lane) shuffle reduce, then LDS across the 4 waves.
    #pragma unroll
    for (int off = 32; off > 0; off >>= 1)
        acc += __shfl_down(acc, off, 64);

    __shared__ float red[4];
    const int wid  = threadIdx.x >> 6;
    const int lane = threadIdx.x & 63;
    if (lane == 0) red[wid] = acc;
    __syncthreads();
    if (threadIdx.x == 0) {
        float s = (red[0] + red[1]) + (red[2] + red[3]);
        sums[cam * C + c] = s;
    }
}

// One block per cam. Builds the label histogram in LDS (integer atomics,
// deterministic), then reduces |avg_conf - avg_count| over C classes.
__global__ __launch_bounds__(1024) void finalize_kernel(
    const float* __restrict__ sums, const int* __restrict__ target,
    float* __restrict__ out)
{
    __shared__ int   cnt[C];
    __shared__ float red[16];

    const int cam = blockIdx.x;

    for (int c = threadIdx.x; c < C; c += 1024) cnt[c] = 0;
    __syncthreads();
    if (threadIdx.x < B) atomicAdd(&cnt[target[threadIdx.x]], 1);
    __syncthreads();

    const float inv_BHW = 1.0f / (float)(B * HW);
    const float inv_B   = 1.0f / (float)B;

    float acc = 0.0f;
    for (int c = threadIdx.x; c < C; c += 1024) {
        const float avg_conf  = sums[cam * C + c] * inv_BHW;
        const float avg_count = (float)cnt[c] * inv_B;
        acc += fabsf(avg_conf - avg_count);
    }

    #pragma unroll
    for (int off = 32; off > 0; off >>= 1)
        acc += __shfl_down(acc, off, 64);

    const int wid  = threadIdx.x >> 6;
    const int lane = threadIdx.x & 63;
    if (lane == 0) red[wid] = acc;
    __syncthreads();
    if (threadIdx.x == 0) {
        float s = 0.0f;
        #pragma unroll
        for (int w = 0; w < 16; ++w) s += red[w];
        out[cam] = s * (1.0f / (float)C);
    }
}

extern "C" void kernel_launch(void* const* d_in, const int* in_sizes, int n_in,
                              void* d_out, int out_size, void* d_ws, size_t ws_size,
                              hipStream_t stream) {
    const float* c0 = (const float*)d_in[0];
    const float* c1 = (const float*)d_in[1];
    const float* c2 = (const float*)d_in[2];
    const float* c3 = (const float*)d_in[3];
    const int*   target = (const int*)d_in[4];

    float* sums = (float*)d_ws;  // 4*1000 floats, fully overwritten each call

    dim3 grid1(C, 4);
    class_sum_kernel<<<grid1, 256, 0, stream>>>(c0, c1, c2, c3, sums);
    finalize_kernel<<<4, 1024, 0, stream>>>(sums, target, (float*)d_out);
}